// Round 10
// baseline (1164.290 us; speedup 1.0000x reference)
//
#include <hip/hip_runtime.h>
#include <hip/hip_bf16.h>
#include <hip/hip_cooperative_groups.h>

namespace cg = cooperative_groups;

#define HDIM 128

typedef __attribute__((ext_vector_type(8))) short bf16x8_t;
typedef __attribute__((ext_vector_type(4))) float f32x4_t;

// ---------- helpers ----------
__device__ inline float bf16u_to_f(unsigned int u) { return __uint_as_float(u << 16); }
__device__ inline unsigned short bf16_rne(float x) {
    union { __hip_bfloat16 b; unsigned short u; } cv;
    cv.b = __float2bfloat16(x);
    return cv.u;
}
__device__ inline void split2(float x, unsigned short& h, unsigned short& l) {
    h = bf16_rne(x);
    l = bf16_rne(x - __uint_as_float((unsigned int)h << 16));
}

// ---------- cooperative CSR build: zero -> histogram -> scan -> rowptr/dis -> fill ----------
// 2048 blocks x 256 threads = 8 blocks/CU (full 32 waves/CU, co-resident)
__global__ __launch_bounds__(256) void csr_build_k(
    const int* __restrict__ src, const int* __restrict__ dst,
    int* __restrict__ deg, int* __restrict__ cursor, int* __restrict__ incl,
    int* __restrict__ blocksum, int* __restrict__ rowptr, int* __restrict__ csr,
    float* __restrict__ dis, int N, int E) {
    cg::grid_group grid = cg::this_grid();
    const int tid = threadIdx.x, bid = blockIdx.x;
    const int gid = bid * 256 + tid;
    const int GSZ = gridDim.x * 256;
    __shared__ int s[256];

    // phase 0: zero deg + cursor
    for (int i = gid; i < N; i += GSZ) { deg[i] = 0; cursor[i] = 0; }
    grid.sync();

    // phase 1: in-degree histogram (full grid, latency-bound -> needs TLP)
    for (int e = gid; e < E; e += GSZ) atomicAdd(&deg[dst[e]], 1);
    grid.sync();

    // phase 2: per-block inclusive scan over deg (only blocks covering [0,N) do real work)
    const int myv = (gid < N) ? deg[gid] : 0;
    s[tid] = myv;
    __syncthreads();
    #pragma unroll
    for (int off = 1; off < 256; off <<= 1) {
        int t = (tid >= off) ? s[tid - off] : 0;
        __syncthreads();
        s[tid] += t;
        __syncthreads();
    }
    if (gid < N) incl[gid] = s[tid];
    if (tid == 255 && bid < 256) blocksum[bid] = s[255];   // NB = ceil(N/256) = 196 <= 256
    grid.sync();

    // phase 3: block 0 exclusive-scans the 256 block sums
    if (bid == 0) {
        const int v2 = blocksum[tid];
        __syncthreads();
        s[tid] = v2;
        __syncthreads();
        #pragma unroll
        for (int off = 1; off < 256; off <<= 1) {
            int t = (tid >= off) ? s[tid - off] : 0;
            __syncthreads();
            s[tid] += t;
            __syncthreads();
        }
        blocksum[tid] = s[tid] - v2;   // exclusive
    }
    grid.sync();

    // phase 4: rowptr + dis
    if (gid < N) {
        rowptr[gid] = blocksum[bid] + incl[gid] - deg[gid];
        dis[gid] = rsqrtf((float)deg[gid] + 1.0f);
    }
    if (gid == 0) rowptr[N] = E;
    grid.sync();

    // phase 5: fill CSR (dst-sorted, cursor atomics)
    for (int e = gid; e < E; e += GSZ) {
        const int d = dst[e];
        const int pos = rowptr[d] + atomicAdd(&cursor[d], 1);
        csr[pos] = src[e];
    }
}

// ---------- weight pack (both layers): fp32 W[128][128] -> MFMA frag-order bf16 hi/lo ----------
__global__ void pack_w2_k(const float* __restrict__ W1, const float* __restrict__ W2,
                          unsigned short* __restrict__ Wp1, unsigned short* __restrict__ Wp2) {
    const int idx = blockIdx.x * 256 + threadIdx.x;   // 32768 total
    const float* W = (idx < 16384) ? W1 : W2;
    unsigned short* hi = (idx < 16384) ? Wp1 : Wp2;
    const int id = idx & 16383;
    const int frag = id >> 9;
    const int r = id & 511;
    const int lane = r >> 3, j = r & 7;
    const int c = frag & 7, sfrag = frag >> 3;
    const int col = (c << 4) | (lane & 15);
    const int k = (sfrag << 5) + ((lane >> 4) << 3) + j;
    unsigned short h, l;
    split2(W[k * HDIM + col], h, l);
    hi[id] = h;
    hi[id + 16384] = l;
}

// ---------- MFMA GEMM: hs = (X @ W) * dis[row]; input fp32 (layer1) or bf16 hi/lo (layer2) ----------
template<bool FP32IN>
__global__ __launch_bounds__(256) void mfma_gemm_k(
    const void* __restrict__ Xin, const unsigned short* __restrict__ Xl,
    const unsigned short* __restrict__ Wp, const float* __restrict__ dis,
    float* __restrict__ hs, int N) {
    __shared__ __align__(16) unsigned short wlds[32768];   // 64 KB: hi, lo
    const int tid = threadIdx.x;
    {
        const float4* wsrc = reinterpret_cast<const float4*>(Wp);
        float4* wdst = reinterpret_cast<float4*>(wlds);
        #pragma unroll
        for (int i = 0; i < 16; ++i) wdst[tid + i * 256] = wsrc[tid + i * 256];
    }
    __syncthreads();

    const int wave = tid >> 6, lane = tid & 63;
    const int row0 = (blockIdx.x << 6) + (wave << 4);
    if (row0 >= N) return;                 // N % 16 == 0
    const int lrow = lane & 15;
    const int kgrp = (lane >> 4) << 3;

    const long abase = ((long)(row0 + lrow) << 7) + kgrp;
    bf16x8_t ah[4], al[4];
    if constexpr (FP32IN) {
        const float* X = (const float*)Xin;
        #pragma unroll
        for (int s = 0; s < 4; ++s) {
            const float4 a0 = *reinterpret_cast<const float4*>(X + abase + (s << 5));
            const float4 a1 = *reinterpret_cast<const float4*>(X + abase + (s << 5) + 4);
            float xv[8] = {a0.x, a0.y, a0.z, a0.w, a1.x, a1.y, a1.z, a1.w};
            #pragma unroll
            for (int j = 0; j < 8; ++j) {
                unsigned short h, l;
                split2(xv[j], h, l);
                ah[s][j] = (short)h;
                al[s][j] = (short)l;
            }
        }
    } else {
        const unsigned short* Xh = (const unsigned short*)Xin;
        #pragma unroll
        for (int s = 0; s < 4; ++s) {
            ah[s] = *reinterpret_cast<const bf16x8_t*>(Xh + abase + (s << 5));
            al[s] = *reinterpret_cast<const bf16x8_t*>(Xl + abase + (s << 5));
        }
    }

    f32x4_t acc[8];
    #pragma unroll
    for (int c = 0; c < 8; ++c) acc[c] = (f32x4_t){0.f, 0.f, 0.f, 0.f};

    #pragma unroll
    for (int s = 0; s < 4; ++s) {
        #pragma unroll
        for (int c = 0; c < 8; ++c) {
            const int fo = (((s << 3) + c) << 9) + (lane << 3);
            const bf16x8_t bh = *reinterpret_cast<const bf16x8_t*>(wlds + fo);
            const bf16x8_t bl = *reinterpret_cast<const bf16x8_t*>(wlds + 16384 + fo);
            acc[c] = __builtin_amdgcn_mfma_f32_16x16x32_bf16(ah[s], bh, acc[c], 0, 0, 0);
            acc[c] = __builtin_amdgcn_mfma_f32_16x16x32_bf16(al[s], bh, acc[c], 0, 0, 0);
            acc[c] = __builtin_amdgcn_mfma_f32_16x16x32_bf16(ah[s], bl, acc[c], 0, 0, 0);
        }
    }

    // C/D: row = (lane>>4)*4 + i, col = c*16 + (lane&15)
    const int rbase = row0 + ((lane >> 4) << 2);
    float d[4];
    #pragma unroll
    for (int i = 0; i < 4; ++i) d[i] = dis[rbase + i];
    #pragma unroll
    for (int c = 0; c < 8; ++c) {
        const int col = (c << 4) | lrow;
        #pragma unroll
        for (int i = 0; i < 4; ++i)
            hs[((long)(rbase + i) << 7) + col] = acc[c][i] * d[i];
    }
}

// ---------- gather-aggregate: one wave per node, 4-deep unroll ----------
// PROJ=false: write bf16 hi/lo h. PROJ=true: write only pu/pv projections (h never materialized)
template<bool PROJ>
__global__ __launch_bounds__(256) void gather_agg_k(
    const int* __restrict__ rowptr, const int* __restrict__ csr,
    const float* __restrict__ hs, const float* __restrict__ dis,
    const float* __restrict__ b, unsigned short* __restrict__ oh,
    unsigned short* __restrict__ ol, const float* __restrict__ Wq,
    float* __restrict__ pu, float* __restrict__ pv, int N) {
    const int lane = threadIdx.x & 63;
    const int wid = (int)((blockIdx.x * (long)blockDim.x + threadIdx.x) >> 6);
    const int nw = (int)(((long)gridDim.x * blockDim.x) >> 6);
    const float2 bb = *reinterpret_cast<const float2*>(&b[lane * 2]);
    float2 wu = {0.f, 0.f}, wv = {0.f, 0.f};
    if constexpr (PROJ) {
        wu = *reinterpret_cast<const float2*>(&Wq[lane * 2]);
        wv = *reinterpret_cast<const float2*>(&Wq[HDIM + lane * 2]);
    }
    const int loff = lane * 2;
    for (int n = wid; n < N; n += nw) {
        const int r0 = rowptr[n], r1 = rowptr[n + 1];
        float2 acc = *reinterpret_cast<const float2*>(&hs[((long)n << 7) + loff]);
        float2 acc2 = {0.f, 0.f};
        int e = r0;
        for (; e + 4 <= r1; e += 4) {
            const int s0 = csr[e], s1 = csr[e + 1], s2 = csr[e + 2], s3 = csr[e + 3];
            const float2 v0 = *reinterpret_cast<const float2*>(&hs[((long)s0 << 7) + loff]);
            const float2 v1 = *reinterpret_cast<const float2*>(&hs[((long)s1 << 7) + loff]);
            const float2 v2 = *reinterpret_cast<const float2*>(&hs[((long)s2 << 7) + loff]);
            const float2 v3 = *reinterpret_cast<const float2*>(&hs[((long)s3 << 7) + loff]);
            acc.x += v0.x + v1.x;
            acc.y += v0.y + v1.y;
            acc2.x += v2.x + v3.x;
            acc2.y += v2.y + v3.y;
        }
        for (; e < r1; ++e) {
            const int s0 = csr[e];
            const float2 v0 = *reinterpret_cast<const float2*>(&hs[((long)s0 << 7) + loff]);
            acc.x += v0.x;
            acc.y += v0.y;
        }
        acc.x += acc2.x;
        acc.y += acc2.y;
        const float dv = dis[n];
        const float o0 = fmaxf(fmaf(acc.x, dv, bb.x), 0.f);
        const float o1 = fmaxf(fmaf(acc.y, dv, bb.y), 0.f);
        if constexpr (!PROJ) {
            ushort2 h, l;
            split2(o0, h.x, l.x);
            split2(o1, h.y, l.y);
            *reinterpret_cast<ushort2*>(oh + ((long)n << 7) + loff) = h;
            *reinterpret_cast<ushort2*>(ol + ((long)n << 7) + loff) = l;
        } else {
            float su = o0 * wu.x + o1 * wu.y;
            float sv = o0 * wv.x + o1 * wv.y;
            #pragma unroll
            for (int off = 32; off > 0; off >>= 1) {
                su += __shfl_down(su, off, 64);
                sv += __shfl_down(sv, off, 64);
            }
            if (lane == 0) {
                pu[n] = su;
                pv[n] = sv;
            }
        }
    }
}

// ---------- Q head: out[a] = pu[va[a,0]] + pv[va[a,1]] + bq ----------
__global__ __launch_bounds__(256) void qhead_k(
    const float* __restrict__ pu, const float* __restrict__ pv,
    const int* __restrict__ va, const float* __restrict__ bq,
    float* __restrict__ out, int A) {
    const float bqv = bq[0];
    int i = blockIdx.x * blockDim.x + threadIdx.x;
    const int stride = gridDim.x * blockDim.x;
    for (; i < A; i += stride) {
        const int2 uv = reinterpret_cast<const int2*>(va)[i];
        out[i] = pu[uv.x] + pv[uv.y] + bqv;
    }
}

extern "C" void kernel_launch(void* const* d_in, const int* in_sizes, int n_in,
                              void* d_out, int out_size, void* d_ws, size_t ws_size,
                              hipStream_t stream) {
    const float* x   = (const float*)d_in[0];
    const int*   ei  = (const int*)d_in[1];     // [2][E] flat: src then dst
    const int*   va  = (const int*)d_in[2];     // [A][2]
    const float* W1  = (const float*)d_in[3];
    const float* b1  = (const float*)d_in[4];
    const float* W2  = (const float*)d_in[5];
    const float* b2  = (const float*)d_in[6];
    const float* Wq  = (const float*)d_in[7];
    const float* bq  = (const float*)d_in[8];
    float* out = (float*)d_out;

    int N = in_sizes[0] / HDIM;       // 50000
    int E = in_sizes[1] / 2;          // 600000
    const int A = in_sizes[2] / 2;    // 200000
    const int* esrc = ei;
    const int* edst = ei + E;

    char* p = (char*)d_ws;
    auto alloc = [&](size_t bytes) { char* r = p; p += (bytes + 255) & ~(size_t)255; return r; };
    int* deg_i    = (int*)alloc((size_t)N * 4);
    int* incl     = (int*)alloc((size_t)N * 4);
    int* rowptr   = (int*)alloc((size_t)(N + 1) * 4);
    int* cursor   = (int*)alloc((size_t)N * 4);
    int* blocksum = (int*)alloc(256 * 4);
    int* csr      = (int*)alloc((size_t)E * 4);
    float* dis    = (float*)alloc((size_t)N * 4);
    float* pu     = (float*)alloc((size_t)N * 4);
    float* pv     = (float*)alloc((size_t)N * 4);
    unsigned short* Wp1 = (unsigned short*)alloc(32768 * 2);
    unsigned short* Wp2 = (unsigned short*)alloc(32768 * 2);
    unsigned short* Xh  = (unsigned short*)alloc((size_t)N * HDIM * 2);
    unsigned short* Xl  = (unsigned short*)alloc((size_t)N * HDIM * 2);
    float* bufA   = (float*)alloc((size_t)N * HDIM * 4);

    const int T = 256;

    // --- CSR build + norms: one cooperative kernel at FULL occupancy (8 blk/CU) ---
    {
        void* args[] = {(void*)&esrc, (void*)&edst, (void*)&deg_i, (void*)&cursor,
                        (void*)&incl, (void*)&blocksum, (void*)&rowptr, (void*)&csr,
                        (void*)&dis, (void*)&N, (void*)&E};
        hipLaunchCooperativeKernel((void*)csr_build_k, dim3(2048), dim3(256), args, 0, stream);
    }

    // --- weight pack (both layers, one kernel) ---
    pack_w2_k<<<128, 256, 0, stream>>>(W1, W2, Wp1, Wp2);

    // --- layer 1: GEMM reads fp32 X directly, in-register bf16 split ---
    mfma_gemm_k<true><<<(N + 63) / 64, 256, 0, stream>>>(x, nullptr, Wp1, dis, bufA, N);
    gather_agg_k<false><<<2048, T, 0, stream>>>(rowptr, csr, bufA, dis, b1,
                                                Xh, Xl, nullptr, nullptr, nullptr, N);

    // --- layer 2: GEMM reads bf16 hi/lo; gather fuses Q-projection epilogue ---
    mfma_gemm_k<false><<<(N + 63) / 64, 256, 0, stream>>>(Xh, Xl, Wp2, dis, bufA, N);
    gather_agg_k<true><<<2048, T, 0, stream>>>(rowptr, csr, bufA, dis, b2,
                                               nullptr, nullptr, Wq, pu, pv, N);

    // --- Q head ---
    qhead_k<<<512, T, 0, stream>>>(pu, pv, va, bq, out, A);
}

// Round 11
// 273.835 us; speedup vs baseline: 4.2518x; 4.2518x over previous
//
#include <hip/hip_runtime.h>
#include <hip/hip_bf16.h>

#define HDIM 128

typedef __attribute__((ext_vector_type(8))) short bf16x8_t;
typedef __attribute__((ext_vector_type(4))) float f32x4_t;

// ---------- helpers ----------
__device__ inline float bf16u_to_f(unsigned int u) { return __uint_as_float(u << 16); }
__device__ inline unsigned short bf16_rne(float x) {
    union { __hip_bfloat16 b; unsigned short u; } cv;
    cv.b = __float2bfloat16(x);
    return cv.u;
}
__device__ inline void split2(float x, unsigned short& h, unsigned short& l) {
    h = bf16_rne(x);
    l = bf16_rne(x - __uint_as_float((unsigned int)h << 16));
}

// ---------- CSR build (split kernels; each tiny, full occupancy) ----------
__global__ void deg_count_k(const int* __restrict__ dst, int* __restrict__ deg, int E) {
    int i = blockIdx.x * blockDim.x + threadIdx.x;
    if (i < E) atomicAdd(&deg[dst[i]], 1);
}

__global__ void scan_part_k(const int* __restrict__ deg, int* __restrict__ incl,
                            int* __restrict__ blocksum, int N) {
    __shared__ int s[256];
    const int tid = threadIdx.x;
    const int i = blockIdx.x * 256 + tid;
    int v = (i < N) ? deg[i] : 0;
    s[tid] = v;
    __syncthreads();
    #pragma unroll
    for (int off = 1; off < 256; off <<= 1) {
        int t = (tid >= off) ? s[tid - off] : 0;
        __syncthreads();
        s[tid] += t;
        __syncthreads();
    }
    if (i < N) incl[i] = s[tid];
    if (tid == 255) blocksum[blockIdx.x] = s[255];
}

__global__ void scan_block_k(int* __restrict__ blocksum, int NB) {
    __shared__ int s[256];
    const int tid = threadIdx.x;
    int v = (tid < NB) ? blocksum[tid] : 0;
    s[tid] = v;
    __syncthreads();
    #pragma unroll
    for (int off = 1; off < 256; off <<= 1) {
        int t = (tid >= off) ? s[tid - off] : 0;
        __syncthreads();
        s[tid] += t;
        __syncthreads();
    }
    if (tid < NB) blocksum[tid] = s[tid] - v;   // exclusive
}

__global__ void scan_final_k(const int* __restrict__ deg, const int* __restrict__ incl,
                             const int* __restrict__ blocksum, int* __restrict__ rowptr,
                             float* __restrict__ dis, int N, int E) {
    const int i = blockIdx.x * 256 + threadIdx.x;
    if (i < N) {
        rowptr[i] = blocksum[blockIdx.x] + incl[i] - deg[i];
        dis[i] = rsqrtf((float)deg[i] + 1.0f);
    }
    if (i == 0) rowptr[N] = E;
}

__global__ void fill_csr_k(const int* __restrict__ src, const int* __restrict__ dst,
                           const int* __restrict__ rowptr, int* __restrict__ cursor,
                           int* __restrict__ csr, int E) {
    int e = blockIdx.x * blockDim.x + threadIdx.x;
    if (e < E) {
        const int d = dst[e];
        const int pos = rowptr[d] + atomicAdd(&cursor[d], 1);
        csr[pos] = src[e];
    }
}

// ---------- weight pack (both layers): fp32 W[128][128] -> MFMA frag-order bf16 hi/lo ----------
__global__ void pack_w2_k(const float* __restrict__ W1, const float* __restrict__ W2,
                          unsigned short* __restrict__ Wp1, unsigned short* __restrict__ Wp2) {
    const int idx = blockIdx.x * 256 + threadIdx.x;   // 32768 total
    const float* W = (idx < 16384) ? W1 : W2;
    unsigned short* hi = (idx < 16384) ? Wp1 : Wp2;
    const int id = idx & 16383;
    const int frag = id >> 9;
    const int r = id & 511;
    const int lane = r >> 3, j = r & 7;
    const int c = frag & 7, sfrag = frag >> 3;
    const int col = (c << 4) | (lane & 15);
    const int k = (sfrag << 5) + ((lane >> 4) << 3) + j;
    unsigned short h, l;
    split2(W[k * HDIM + col], h, l);
    hi[id] = h;
    hi[id + 16384] = l;
}

// ---------- MFMA GEMM: hs = (X @ W) * dis[row]; input fp32 (layer1) or bf16 hi/lo (layer2) ----------
template<bool FP32IN>
__global__ __launch_bounds__(256) void mfma_gemm_k(
    const void* __restrict__ Xin, const unsigned short* __restrict__ Xl,
    const unsigned short* __restrict__ Wp, const float* __restrict__ dis,
    float* __restrict__ hs, int N) {
    __shared__ __align__(16) unsigned short wlds[32768];   // 64 KB: hi, lo
    const int tid = threadIdx.x;
    {
        const float4* wsrc = reinterpret_cast<const float4*>(Wp);
        float4* wdst = reinterpret_cast<float4*>(wlds);
        #pragma unroll
        for (int i = 0; i < 16; ++i) wdst[tid + i * 256] = wsrc[tid + i * 256];
    }
    __syncthreads();

    const int wave = tid >> 6, lane = tid & 63;
    const int row0 = (blockIdx.x << 6) + (wave << 4);
    if (row0 >= N) return;                 // N % 16 == 0
    const int lrow = lane & 15;
    const int kgrp = (lane >> 4) << 3;

    const long abase = ((long)(row0 + lrow) << 7) + kgrp;
    bf16x8_t ah[4], al[4];
    if constexpr (FP32IN) {
        const float* X = (const float*)Xin;
        #pragma unroll
        for (int s = 0; s < 4; ++s) {
            const float4 a0 = *reinterpret_cast<const float4*>(X + abase + (s << 5));
            const float4 a1 = *reinterpret_cast<const float4*>(X + abase + (s << 5) + 4);
            float xv[8] = {a0.x, a0.y, a0.z, a0.w, a1.x, a1.y, a1.z, a1.w};
            #pragma unroll
            for (int j = 0; j < 8; ++j) {
                unsigned short h, l;
                split2(xv[j], h, l);
                ah[s][j] = (short)h;
                al[s][j] = (short)l;
            }
        }
    } else {
        const unsigned short* Xh = (const unsigned short*)Xin;
        #pragma unroll
        for (int s = 0; s < 4; ++s) {
            ah[s] = *reinterpret_cast<const bf16x8_t*>(Xh + abase + (s << 5));
            al[s] = *reinterpret_cast<const bf16x8_t*>(Xl + abase + (s << 5));
        }
    }

    f32x4_t acc[8];
    #pragma unroll
    for (int c = 0; c < 8; ++c) acc[c] = (f32x4_t){0.f, 0.f, 0.f, 0.f};

    #pragma unroll
    for (int s = 0; s < 4; ++s) {
        #pragma unroll
        for (int c = 0; c < 8; ++c) {
            const int fo = (((s << 3) + c) << 9) + (lane << 3);
            const bf16x8_t bh = *reinterpret_cast<const bf16x8_t*>(wlds + fo);
            const bf16x8_t bl = *reinterpret_cast<const bf16x8_t*>(wlds + 16384 + fo);
            acc[c] = __builtin_amdgcn_mfma_f32_16x16x32_bf16(ah[s], bh, acc[c], 0, 0, 0);
            acc[c] = __builtin_amdgcn_mfma_f32_16x16x32_bf16(al[s], bh, acc[c], 0, 0, 0);
            acc[c] = __builtin_amdgcn_mfma_f32_16x16x32_bf16(ah[s], bl, acc[c], 0, 0, 0);
        }
    }

    // C/D: row = (lane>>4)*4 + i, col = c*16 + (lane&15)
    const int rbase = row0 + ((lane >> 4) << 2);
    float d[4];
    #pragma unroll
    for (int i = 0; i < 4; ++i) d[i] = dis[rbase + i];
    #pragma unroll
    for (int c = 0; c < 8; ++c) {
        const int col = (c << 4) | lrow;
        #pragma unroll
        for (int i = 0; i < 4; ++i)
            hs[((long)(rbase + i) << 7) + col] = acc[c][i] * d[i];
    }
}

// ---------- gather-aggregate: one wave per node, 4-deep unroll ----------
// PROJ=false: write bf16 hi/lo h. PROJ=true: write only pu/pv projections (h never materialized)
template<bool PROJ>
__global__ __launch_bounds__(256) void gather_agg_k(
    const int* __restrict__ rowptr, const int* __restrict__ csr,
    const float* __restrict__ hs, const float* __restrict__ dis,
    const float* __restrict__ b, unsigned short* __restrict__ oh,
    unsigned short* __restrict__ ol, const float* __restrict__ Wq,
    float* __restrict__ pu, float* __restrict__ pv, int N) {
    const int lane = threadIdx.x & 63;
    const int wid = (int)((blockIdx.x * (long)blockDim.x + threadIdx.x) >> 6);
    const int nw = (int)(((long)gridDim.x * blockDim.x) >> 6);
    const float2 bb = *reinterpret_cast<const float2*>(&b[lane * 2]);
    float2 wu = {0.f, 0.f}, wv = {0.f, 0.f};
    if constexpr (PROJ) {
        wu = *reinterpret_cast<const float2*>(&Wq[lane * 2]);
        wv = *reinterpret_cast<const float2*>(&Wq[HDIM + lane * 2]);
    }
    const int loff = lane * 2;
    for (int n = wid; n < N; n += nw) {
        const int r0 = rowptr[n], r1 = rowptr[n + 1];
        float2 acc = *reinterpret_cast<const float2*>(&hs[((long)n << 7) + loff]);
        float2 acc2 = {0.f, 0.f};
        int e = r0;
        for (; e + 4 <= r1; e += 4) {
            const int s0 = csr[e], s1 = csr[e + 1], s2 = csr[e + 2], s3 = csr[e + 3];
            const float2 v0 = *reinterpret_cast<const float2*>(&hs[((long)s0 << 7) + loff]);
            const float2 v1 = *reinterpret_cast<const float2*>(&hs[((long)s1 << 7) + loff]);
            const float2 v2 = *reinterpret_cast<const float2*>(&hs[((long)s2 << 7) + loff]);
            const float2 v3 = *reinterpret_cast<const float2*>(&hs[((long)s3 << 7) + loff]);
            acc.x += v0.x + v1.x;
            acc.y += v0.y + v1.y;
            acc2.x += v2.x + v3.x;
            acc2.y += v2.y + v3.y;
        }
        for (; e < r1; ++e) {
            const int s0 = csr[e];
            const float2 v0 = *reinterpret_cast<const float2*>(&hs[((long)s0 << 7) + loff]);
            acc.x += v0.x;
            acc.y += v0.y;
        }
        acc.x += acc2.x;
        acc.y += acc2.y;
        const float dv = dis[n];
        const float o0 = fmaxf(fmaf(acc.x, dv, bb.x), 0.f);
        const float o1 = fmaxf(fmaf(acc.y, dv, bb.y), 0.f);
        if constexpr (!PROJ) {
            ushort2 h, l;
            split2(o0, h.x, l.x);
            split2(o1, h.y, l.y);
            *reinterpret_cast<ushort2*>(oh + ((long)n << 7) + loff) = h;
            *reinterpret_cast<ushort2*>(ol + ((long)n << 7) + loff) = l;
        } else {
            float su = o0 * wu.x + o1 * wu.y;
            float sv = o0 * wv.x + o1 * wv.y;
            #pragma unroll
            for (int off = 32; off > 0; off >>= 1) {
                su += __shfl_down(su, off, 64);
                sv += __shfl_down(sv, off, 64);
            }
            if (lane == 0) {
                pu[n] = su;
                pv[n] = sv;
            }
        }
    }
}

// ---------- Q head: out[a] = pu[va[a,0]] + pv[va[a,1]] + bq ----------
__global__ __launch_bounds__(256) void qhead_k(
    const float* __restrict__ pu, const float* __restrict__ pv,
    const int* __restrict__ va, const float* __restrict__ bq,
    float* __restrict__ out, int A) {
    const float bqv = bq[0];
    int i = blockIdx.x * blockDim.x + threadIdx.x;
    const int stride = gridDim.x * blockDim.x;
    for (; i < A; i += stride) {
        const int2 uv = reinterpret_cast<const int2*>(va)[i];
        out[i] = pu[uv.x] + pv[uv.y] + bqv;
    }
}

extern "C" void kernel_launch(void* const* d_in, const int* in_sizes, int n_in,
                              void* d_out, int out_size, void* d_ws, size_t ws_size,
                              hipStream_t stream) {
    const float* x   = (const float*)d_in[0];
    const int*   ei  = (const int*)d_in[1];     // [2][E] flat: src then dst
    const int*   va  = (const int*)d_in[2];     // [A][2]
    const float* W1  = (const float*)d_in[3];
    const float* b1  = (const float*)d_in[4];
    const float* W2  = (const float*)d_in[5];
    const float* b2  = (const float*)d_in[6];
    const float* Wq  = (const float*)d_in[7];
    const float* bq  = (const float*)d_in[8];
    float* out = (float*)d_out;

    const int N = in_sizes[0] / HDIM;       // 50000
    const int E = in_sizes[1] / 2;          // 600000
    const int A = in_sizes[2] / 2;          // 200000
    const int* esrc = ei;
    const int* edst = ei + E;

    const int Nal = (N + 63) & ~63;

    char* p = (char*)d_ws;
    auto alloc = [&](size_t bytes) { char* r = p; p += (bytes + 255) & ~(size_t)255; return r; };
    int* deg_i    = (int*)alloc((size_t)Nal * 4 * 2);  // deg | cursor adjacent -> one memset
    int* cursor   = deg_i + Nal;
    int* incl     = (int*)alloc((size_t)N * 4);
    int* rowptr   = (int*)alloc((size_t)(N + 1) * 4);
    int* blocksum = (int*)alloc(256 * 4);
    int* csr      = (int*)alloc((size_t)E * 4);
    float* dis    = (float*)alloc((size_t)N * 4);
    float* pu     = (float*)alloc((size_t)N * 4);
    float* pv     = (float*)alloc((size_t)N * 4);
    unsigned short* Wp1 = (unsigned short*)alloc(32768 * 2);
    unsigned short* Wp2 = (unsigned short*)alloc(32768 * 2);
    unsigned short* Xh  = (unsigned short*)alloc((size_t)N * HDIM * 2);
    unsigned short* Xl  = (unsigned short*)alloc((size_t)N * HDIM * 2);
    float* bufA   = (float*)alloc((size_t)N * HDIM * 4);

    const int T = 256;
    const int NB = (N + 255) / 256;          // 196 (<= 256 required by scan_block_k)

    // --- CSR build + norms (split kernels; grid.sync proved pathological in R10) ---
    hipMemsetAsync(deg_i, 0, (size_t)Nal * 4 * 2, stream);   // deg + cursor in one shot
    deg_count_k<<<(E + T - 1) / T, T, 0, stream>>>(edst, deg_i, E);
    scan_part_k<<<NB, 256, 0, stream>>>(deg_i, incl, blocksum, N);
    scan_block_k<<<1, 256, 0, stream>>>(blocksum, NB);
    scan_final_k<<<NB, 256, 0, stream>>>(deg_i, incl, blocksum, rowptr, dis, N, E);
    fill_csr_k<<<(E + T - 1) / T, T, 0, stream>>>(esrc, edst, rowptr, cursor, csr, E);

    // --- weight pack (both layers, one kernel) ---
    pack_w2_k<<<128, 256, 0, stream>>>(W1, W2, Wp1, Wp2);

    // --- layer 1: GEMM reads fp32 X directly, in-register bf16 split ---
    mfma_gemm_k<true><<<(N + 63) / 64, 256, 0, stream>>>(x, nullptr, Wp1, dis, bufA, N);
    gather_agg_k<false><<<2048, T, 0, stream>>>(rowptr, csr, bufA, dis, b1,
                                                Xh, Xl, nullptr, nullptr, nullptr, N);

    // --- layer 2: GEMM reads bf16 hi/lo; gather fuses Q-projection epilogue ---
    mfma_gemm_k<false><<<(N + 63) / 64, 256, 0, stream>>>(Xh, Xl, Wp2, dis, bufA, N);
    gather_agg_k<true><<<2048, T, 0, stream>>>(rowptr, csr, bufA, dis, b2,
                                               nullptr, nullptr, Wq, pu, pv, N);

    // --- Q head ---
    qhead_k<<<512, T, 0, stream>>>(pu, pv, va, bq, out, A);
}

// Round 12
// 271.026 us; speedup vs baseline: 4.2959x; 1.0104x over previous
//
#include <hip/hip_runtime.h>
#include <hip/hip_bf16.h>

#define HDIM 128

typedef __attribute__((ext_vector_type(8))) short bf16x8_t;
typedef __attribute__((ext_vector_type(4))) float f32x4_t;

// ---------- helpers ----------
__device__ inline unsigned short bf16_rne(float x) {
    union { __hip_bfloat16 b; unsigned short u; } cv;
    cv.b = __float2bfloat16(x);
    return cv.u;
}
__device__ inline void split2(float x, unsigned short& h, unsigned short& l) {
    h = bf16_rne(x);
    l = bf16_rne(x - __uint_as_float((unsigned int)h << 16));
}

// ---------- CSR build (split kernels; each tiny, full occupancy) ----------
__global__ void deg_count_k(const int* __restrict__ dst, int* __restrict__ deg, int E) {
    int i = blockIdx.x * blockDim.x + threadIdx.x;
    if (i < E) atomicAdd(&deg[dst[i]], 1);
}

__global__ void scan_part_k(const int* __restrict__ deg, int* __restrict__ incl,
                            int* __restrict__ blocksum, int N) {
    __shared__ int s[256];
    const int tid = threadIdx.x;
    const int i = blockIdx.x * 256 + tid;
    int v = (i < N) ? deg[i] : 0;
    s[tid] = v;
    __syncthreads();
    #pragma unroll
    for (int off = 1; off < 256; off <<= 1) {
        int t = (tid >= off) ? s[tid - off] : 0;
        __syncthreads();
        s[tid] += t;
        __syncthreads();
    }
    if (i < N) incl[i] = s[tid];
    if (tid == 255) blocksum[blockIdx.x] = s[255];
}

// merged: every block scans the <=256 block sums in LDS, then writes rowptr + dis
__global__ void scan_final_k(const int* __restrict__ deg, const int* __restrict__ incl,
                             const int* __restrict__ blocksum, int* __restrict__ rowptr,
                             float* __restrict__ dis, int N, int E, int NB) {
    __shared__ int s[256];
    const int tid = threadIdx.x, bid = blockIdx.x;
    const int i = bid * 256 + tid;
    const int v = (tid < NB) ? blocksum[tid] : 0;
    s[tid] = v;
    __syncthreads();
    #pragma unroll
    for (int off = 1; off < 256; off <<= 1) {
        int t = (tid >= off) ? s[tid - off] : 0;
        __syncthreads();
        s[tid] += t;
        __syncthreads();
    }
    // exclusive prefix of blocksum for this block: inclusive(bid) - own
    const int excl = s[bid] - blocksum[bid];   // bid < NB always (grid = NB blocks)
    if (i < N) {
        rowptr[i] = excl + incl[i] - deg[i];
        dis[i] = rsqrtf((float)deg[i] + 1.0f);
    }
    if (i == 0) rowptr[N] = E;
}

__global__ void fill_csr_k(const int* __restrict__ src, const int* __restrict__ dst,
                           const int* __restrict__ rowptr, int* __restrict__ cursor,
                           int* __restrict__ csr, int E) {
    int e = blockIdx.x * blockDim.x + threadIdx.x;
    if (e < E) {
        const int d = dst[e];
        const int pos = rowptr[d] + atomicAdd(&cursor[d], 1);
        csr[pos] = src[e];
    }
}

// ---------- weight pack (both layers): fp32 W[128][128] -> MFMA frag-order bf16 hi/lo ----------
__global__ void pack_w2_k(const float* __restrict__ W1, const float* __restrict__ W2,
                          unsigned short* __restrict__ Wp1, unsigned short* __restrict__ Wp2) {
    const int idx = blockIdx.x * 256 + threadIdx.x;   // 32768 total
    const float* W = (idx < 16384) ? W1 : W2;
    unsigned short* hi = (idx < 16384) ? Wp1 : Wp2;
    const int id = idx & 16383;
    const int frag = id >> 9;
    const int r = id & 511;
    const int lane = r >> 3, j = r & 7;
    const int c = frag & 7, sfrag = frag >> 3;
    const int col = (c << 4) | (lane & 15);
    const int k = (sfrag << 5) + ((lane >> 4) << 3) + j;
    unsigned short h, l;
    split2(W[k * HDIM + col], h, l);
    hi[id] = h;
    hi[id + 16384] = l;
}

// ---------- MFMA GEMM: hs = (X @ W) * dis[row]; fp32 input, in-register bf16 split ----------
__global__ __launch_bounds__(256) void mfma_gemm_k(
    const float* __restrict__ X, const unsigned short* __restrict__ Wp,
    const float* __restrict__ dis, float* __restrict__ hs, int N) {
    __shared__ __align__(16) unsigned short wlds[32768];   // 64 KB: hi, lo
    const int tid = threadIdx.x;
    {
        const float4* wsrc = reinterpret_cast<const float4*>(Wp);
        float4* wdst = reinterpret_cast<float4*>(wlds);
        #pragma unroll
        for (int i = 0; i < 16; ++i) wdst[tid + i * 256] = wsrc[tid + i * 256];
    }
    __syncthreads();

    const int wave = tid >> 6, lane = tid & 63;
    const int row0 = (blockIdx.x << 6) + (wave << 4);
    if (row0 >= N) return;                 // N % 16 == 0
    const int lrow = lane & 15;
    const int kgrp = (lane >> 4) << 3;

    const long abase = ((long)(row0 + lrow) << 7) + kgrp;
    bf16x8_t ah[4], al[4];
    #pragma unroll
    for (int s = 0; s < 4; ++s) {
        const float4 a0 = *reinterpret_cast<const float4*>(X + abase + (s << 5));
        const float4 a1 = *reinterpret_cast<const float4*>(X + abase + (s << 5) + 4);
        float xv[8] = {a0.x, a0.y, a0.z, a0.w, a1.x, a1.y, a1.z, a1.w};
        #pragma unroll
        for (int j = 0; j < 8; ++j) {
            unsigned short h, l;
            split2(xv[j], h, l);
            ah[s][j] = (short)h;
            al[s][j] = (short)l;
        }
    }

    f32x4_t acc[8];
    #pragma unroll
    for (int c = 0; c < 8; ++c) acc[c] = (f32x4_t){0.f, 0.f, 0.f, 0.f};

    #pragma unroll
    for (int s = 0; s < 4; ++s) {
        #pragma unroll
        for (int c = 0; c < 8; ++c) {
            const int fo = (((s << 3) + c) << 9) + (lane << 3);
            const bf16x8_t bh = *reinterpret_cast<const bf16x8_t*>(wlds + fo);
            const bf16x8_t bl = *reinterpret_cast<const bf16x8_t*>(wlds + 16384 + fo);
            acc[c] = __builtin_amdgcn_mfma_f32_16x16x32_bf16(ah[s], bh, acc[c], 0, 0, 0);
            acc[c] = __builtin_amdgcn_mfma_f32_16x16x32_bf16(al[s], bh, acc[c], 0, 0, 0);
            acc[c] = __builtin_amdgcn_mfma_f32_16x16x32_bf16(ah[s], bl, acc[c], 0, 0, 0);
        }
    }

    // C/D: row = (lane>>4)*4 + i, col = c*16 + (lane&15)
    const int rbase = row0 + ((lane >> 4) << 2);
    float d[4];
    #pragma unroll
    for (int i = 0; i < 4; ++i) d[i] = dis[rbase + i];
    #pragma unroll
    for (int c = 0; c < 8; ++c) {
        const int col = (c << 4) | lrow;
        #pragma unroll
        for (int i = 0; i < 4; ++i)
            hs[((long)(rbase + i) << 7) + col] = acc[c][i] * d[i];
    }
}

// ---------- gather-aggregate: one wave per node, 8-deep edge unroll ----------
// PROJ=false: write fp32 h. PROJ=true: write only pu/pv projections (h never materialized)
template<bool PROJ>
__global__ __launch_bounds__(256) void gather_agg_k(
    const int* __restrict__ rowptr, const int* __restrict__ csr,
    const float* __restrict__ hs, const float* __restrict__ dis,
    const float* __restrict__ b, float* __restrict__ o,
    const float* __restrict__ Wq, float* __restrict__ pu, float* __restrict__ pv, int N) {
    const int lane = threadIdx.x & 63;
    const int wid = (int)((blockIdx.x * (long)blockDim.x + threadIdx.x) >> 6);
    const int nw = (int)(((long)gridDim.x * blockDim.x) >> 6);
    const float2 bb = *reinterpret_cast<const float2*>(&b[lane * 2]);
    float2 wu = {0.f, 0.f}, wv = {0.f, 0.f};
    if constexpr (PROJ) {
        wu = *reinterpret_cast<const float2*>(&Wq[lane * 2]);
        wv = *reinterpret_cast<const float2*>(&Wq[HDIM + lane * 2]);
    }
    const int loff = lane * 2;
    for (int n = wid; n < N; n += nw) {
        const int r0 = rowptr[n], r1 = rowptr[n + 1];
        float2 acc = *reinterpret_cast<const float2*>(&hs[((long)n << 7) + loff]);
        float2 acc2 = {0.f, 0.f};
        int e = r0;
        for (; e + 8 <= r1; e += 8) {
            const int s0 = csr[e],     s1 = csr[e + 1], s2 = csr[e + 2], s3 = csr[e + 3];
            const int s4 = csr[e + 4], s5 = csr[e + 5], s6 = csr[e + 6], s7 = csr[e + 7];
            const float2 v0 = *reinterpret_cast<const float2*>(&hs[((long)s0 << 7) + loff]);
            const float2 v1 = *reinterpret_cast<const float2*>(&hs[((long)s1 << 7) + loff]);
            const float2 v2 = *reinterpret_cast<const float2*>(&hs[((long)s2 << 7) + loff]);
            const float2 v3 = *reinterpret_cast<const float2*>(&hs[((long)s3 << 7) + loff]);
            const float2 v4 = *reinterpret_cast<const float2*>(&hs[((long)s4 << 7) + loff]);
            const float2 v5 = *reinterpret_cast<const float2*>(&hs[((long)s5 << 7) + loff]);
            const float2 v6 = *reinterpret_cast<const float2*>(&hs[((long)s6 << 7) + loff]);
            const float2 v7 = *reinterpret_cast<const float2*>(&hs[((long)s7 << 7) + loff]);
            acc.x  += v0.x + v1.x;  acc.y  += v0.y + v1.y;
            acc2.x += v2.x + v3.x;  acc2.y += v2.y + v3.y;
            acc.x  += v4.x + v5.x;  acc.y  += v4.y + v5.y;
            acc2.x += v6.x + v7.x;  acc2.y += v6.y + v7.y;
        }
        for (; e + 2 <= r1; e += 2) {
            const int s0 = csr[e], s1 = csr[e + 1];
            const float2 v0 = *reinterpret_cast<const float2*>(&hs[((long)s0 << 7) + loff]);
            const float2 v1 = *reinterpret_cast<const float2*>(&hs[((long)s1 << 7) + loff]);
            acc.x += v0.x + v1.x;
            acc.y += v0.y + v1.y;
        }
        if (e < r1) {
            const int s0 = csr[e];
            const float2 v0 = *reinterpret_cast<const float2*>(&hs[((long)s0 << 7) + loff]);
            acc.x += v0.x;
            acc.y += v0.y;
        }
        acc.x += acc2.x;
        acc.y += acc2.y;
        const float dv = dis[n];
        const float o0 = fmaxf(fmaf(acc.x, dv, bb.x), 0.f);
        const float o1 = fmaxf(fmaf(acc.y, dv, bb.y), 0.f);
        if constexpr (!PROJ) {
            float2 ov = {o0, o1};
            *reinterpret_cast<float2*>(o + ((long)n << 7) + loff) = ov;
        } else {
            float su = o0 * wu.x + o1 * wu.y;
            float sv = o0 * wv.x + o1 * wv.y;
            #pragma unroll
            for (int off = 32; off > 0; off >>= 1) {
                su += __shfl_down(su, off, 64);
                sv += __shfl_down(sv, off, 64);
            }
            if (lane == 0) {
                pu[n] = su;
                pv[n] = sv;
            }
        }
    }
}

// ---------- Q head: out[a] = pu[va[a,0]] + pv[va[a,1]] + bq ----------
__global__ __launch_bounds__(256) void qhead_k(
    const float* __restrict__ pu, const float* __restrict__ pv,
    const int* __restrict__ va, const float* __restrict__ bq,
    float* __restrict__ out, int A) {
    const float bqv = bq[0];
    int i = blockIdx.x * blockDim.x + threadIdx.x;
    const int stride = gridDim.x * blockDim.x;
    for (; i < A; i += stride) {
        const int2 uv = reinterpret_cast<const int2*>(va)[i];
        out[i] = pu[uv.x] + pv[uv.y] + bqv;
    }
}

extern "C" void kernel_launch(void* const* d_in, const int* in_sizes, int n_in,
                              void* d_out, int out_size, void* d_ws, size_t ws_size,
                              hipStream_t stream) {
    const float* x   = (const float*)d_in[0];
    const int*   ei  = (const int*)d_in[1];     // [2][E] flat: src then dst
    const int*   va  = (const int*)d_in[2];     // [A][2]
    const float* W1  = (const float*)d_in[3];
    const float* b1  = (const float*)d_in[4];
    const float* W2  = (const float*)d_in[5];
    const float* b2  = (const float*)d_in[6];
    const float* Wq  = (const float*)d_in[7];
    const float* bq  = (const float*)d_in[8];
    float* out = (float*)d_out;

    const int N = in_sizes[0] / HDIM;       // 50000
    const int E = in_sizes[1] / 2;          // 600000
    const int A = in_sizes[2] / 2;          // 200000
    const int* esrc = ei;
    const int* edst = ei + E;

    const int Nal = (N + 63) & ~63;

    char* p = (char*)d_ws;
    auto alloc = [&](size_t bytes) { char* r = p; p += (bytes + 255) & ~(size_t)255; return r; };
    int* deg_i    = (int*)alloc((size_t)Nal * 4 * 2);  // deg | cursor adjacent -> one memset
    int* cursor   = deg_i + Nal;
    int* incl     = (int*)alloc((size_t)N * 4);
    int* rowptr   = (int*)alloc((size_t)(N + 1) * 4);
    int* blocksum = (int*)alloc(256 * 4);
    int* csr      = (int*)alloc((size_t)E * 4);
    float* dis    = (float*)alloc((size_t)N * 4);
    float* pu     = (float*)alloc((size_t)N * 4);
    float* pv     = (float*)alloc((size_t)N * 4);
    unsigned short* Wp1 = (unsigned short*)alloc(32768 * 2);
    unsigned short* Wp2 = (unsigned short*)alloc(32768 * 2);
    float* bufA   = (float*)alloc((size_t)N * HDIM * 4);   // hs (scaled GEMM out)
    float* bufB   = (float*)alloc((size_t)N * HDIM * 4);   // h1 fp32

    const int T = 256;
    const int NB = (N + 255) / 256;          // 196 (<= 256 required by merged scan)

    // --- CSR build + norms ---
    hipMemsetAsync(deg_i, 0, (size_t)Nal * 4 * 2, stream);   // deg + cursor in one shot
    deg_count_k<<<(E + T - 1) / T, T, 0, stream>>>(edst, deg_i, E);
    scan_part_k<<<NB, 256, 0, stream>>>(deg_i, incl, blocksum, N);
    scan_final_k<<<NB, 256, 0, stream>>>(deg_i, incl, blocksum, rowptr, dis, N, E, NB);
    fill_csr_k<<<(E + T - 1) / T, T, 0, stream>>>(esrc, edst, rowptr, cursor, csr, E);

    // --- weight pack (both layers, one kernel) ---
    pack_w2_k<<<128, 256, 0, stream>>>(W1, W2, Wp1, Wp2);

    // --- layer 1 ---
    mfma_gemm_k<<<(N + 63) / 64, 256, 0, stream>>>(x, Wp1, dis, bufA, N);
    gather_agg_k<false><<<2048, T, 0, stream>>>(rowptr, csr, bufA, dis, b1,
                                                bufB, nullptr, nullptr, nullptr, N);

    // --- layer 2 (gather fuses Q-projection epilogue; h2 never materialized) ---
    mfma_gemm_k<<<(N + 63) / 64, 256, 0, stream>>>(bufB, Wp2, dis, bufA, N);
    gather_agg_k<true><<<2048, T, 0, stream>>>(rowptr, csr, bufA, dis, b2,
                                               nullptr, Wq, pu, pv, N);

    // --- Q head ---
    qhead_k<<<512, T, 0, stream>>>(pu, pv, va, bq, out, A);
}

// Round 13
// 269.670 us; speedup vs baseline: 4.3175x; 1.0050x over previous
//
#include <hip/hip_runtime.h>
#include <hip/hip_bf16.h>

#define HDIM 128

typedef __attribute__((ext_vector_type(8))) short bf16x8_t;
typedef __attribute__((ext_vector_type(4))) float f32x4_t;

// ---------- helpers ----------
__device__ inline unsigned short bf16_rne(float x) {
    union { __hip_bfloat16 b; unsigned short u; } cv;
    cv.b = __float2bfloat16(x);
    return cv.u;
}
__device__ inline void split2(float x, unsigned short& h, unsigned short& l) {
    h = bf16_rne(x);
    l = bf16_rne(x - __uint_as_float((unsigned int)h << 16));
}

// ---------- CSR build (split kernels; each tiny, full occupancy) ----------
__global__ void deg_count_k(const int* __restrict__ dst, int* __restrict__ deg, int E) {
    int i = blockIdx.x * blockDim.x + threadIdx.x;
    if (i < E) atomicAdd(&deg[dst[i]], 1);
}

__global__ void scan_part_k(const int* __restrict__ deg, int* __restrict__ incl,
                            int* __restrict__ blocksum, int N) {
    __shared__ int s[256];
    const int tid = threadIdx.x;
    const int i = blockIdx.x * 256 + tid;
    int v = (i < N) ? deg[i] : 0;
    s[tid] = v;
    __syncthreads();
    #pragma unroll
    for (int off = 1; off < 256; off <<= 1) {
        int t = (tid >= off) ? s[tid - off] : 0;
        __syncthreads();
        s[tid] += t;
        __syncthreads();
    }
    if (i < N) incl[i] = s[tid];
    if (tid == 255) blocksum[blockIdx.x] = s[255];
}

// merged: every block scans the <=256 block sums in LDS, then writes rowptr + dis
__global__ void scan_final_k(const int* __restrict__ deg, const int* __restrict__ incl,
                             const int* __restrict__ blocksum, int* __restrict__ rowptr,
                             float* __restrict__ dis, int N, int E, int NB) {
    __shared__ int s[256];
    const int tid = threadIdx.x, bid = blockIdx.x;
    const int i = bid * 256 + tid;
    const int v = (tid < NB) ? blocksum[tid] : 0;
    s[tid] = v;
    __syncthreads();
    #pragma unroll
    for (int off = 1; off < 256; off <<= 1) {
        int t = (tid >= off) ? s[tid - off] : 0;
        __syncthreads();
        s[tid] += t;
        __syncthreads();
    }
    const int excl = s[bid] - blocksum[bid];   // bid < NB always (grid = NB blocks)
    if (i < N) {
        rowptr[i] = excl + incl[i] - deg[i];
        dis[i] = rsqrtf((float)deg[i] + 1.0f);
    }
    if (i == 0) rowptr[N] = E;
}

__global__ void fill_csr_k(const int* __restrict__ src, const int* __restrict__ dst,
                           const int* __restrict__ rowptr, int* __restrict__ cursor,
                           int* __restrict__ csr, int E) {
    int e = blockIdx.x * blockDim.x + threadIdx.x;
    if (e < E) {
        const int d = dst[e];
        const int pos = rowptr[d] + atomicAdd(&cursor[d], 1);
        csr[pos] = src[e];
    }
}

// ---------- weight pack (both layers): fp32 W[128][128] -> MFMA frag-order bf16 hi/lo ----------
__global__ void pack_w2_k(const float* __restrict__ W1, const float* __restrict__ W2,
                          unsigned short* __restrict__ Wp1, unsigned short* __restrict__ Wp2) {
    const int idx = blockIdx.x * 256 + threadIdx.x;   // 32768 total
    const float* W = (idx < 16384) ? W1 : W2;
    unsigned short* hi = (idx < 16384) ? Wp1 : Wp2;
    const int id = idx & 16383;
    const int frag = id >> 9;
    const int r = id & 511;
    const int lane = r >> 3, j = r & 7;
    const int c = frag & 7, sfrag = frag >> 3;
    const int col = (c << 4) | (lane & 15);
    const int k = (sfrag << 5) + ((lane >> 4) << 3) + j;
    unsigned short h, l;
    split2(W[k * HDIM + col], h, l);
    hi[id] = h;
    hi[id + 16384] = l;
}

// ---------- MFMA GEMM: hs = (X @ W) * dis[row]; fp32 input, in-register bf16 split ----------
// 512 thr = 8 waves = 128 rows/block; 64KB W-LDS -> 2 blocks/CU = 16 waves/CU
__global__ __launch_bounds__(512, 4) void mfma_gemm_k(
    const float* __restrict__ X, const unsigned short* __restrict__ Wp,
    const float* __restrict__ dis, float* __restrict__ hs, int N) {
    __shared__ __align__(16) unsigned short wlds[32768];   // 64 KB: hi, lo
    const int tid = threadIdx.x;
    {
        const float4* wsrc = reinterpret_cast<const float4*>(Wp);
        float4* wdst = reinterpret_cast<float4*>(wlds);
        #pragma unroll
        for (int i = 0; i < 8; ++i) wdst[tid + i * 512] = wsrc[tid + i * 512];
    }
    __syncthreads();

    const int wave = tid >> 6, lane = tid & 63;
    const int row0 = (blockIdx.x << 7) + (wave << 4);
    if (row0 >= N) return;                 // N % 16 == 0: tiles fully in or out
    const int lrow = lane & 15;
    const int kgrp = (lane >> 4) << 3;

    const long abase = ((long)(row0 + lrow) << 7) + kgrp;

    f32x4_t acc[8];
    #pragma unroll
    for (int c = 0; c < 8; ++c) acc[c] = (f32x4_t){0.f, 0.f, 0.f, 0.f};

    #pragma unroll
    for (int s = 0; s < 4; ++s) {
        // load + split this k-slice only (keeps live VGPR low)
        const float4 a0 = *reinterpret_cast<const float4*>(X + abase + (s << 5));
        const float4 a1 = *reinterpret_cast<const float4*>(X + abase + (s << 5) + 4);
        const float xv[8] = {a0.x, a0.y, a0.z, a0.w, a1.x, a1.y, a1.z, a1.w};
        bf16x8_t ah, al;
        #pragma unroll
        for (int j = 0; j < 8; ++j) {
            unsigned short h, l;
            split2(xv[j], h, l);
            ah[j] = (short)h;
            al[j] = (short)l;
        }
        #pragma unroll
        for (int c = 0; c < 8; ++c) {
            const int fo = (((s << 3) + c) << 9) + (lane << 3);
            const bf16x8_t bh = *reinterpret_cast<const bf16x8_t*>(wlds + fo);
            const bf16x8_t bl = *reinterpret_cast<const bf16x8_t*>(wlds + 16384 + fo);
            acc[c] = __builtin_amdgcn_mfma_f32_16x16x32_bf16(ah, bh, acc[c], 0, 0, 0);
            acc[c] = __builtin_amdgcn_mfma_f32_16x16x32_bf16(al, bh, acc[c], 0, 0, 0);
            acc[c] = __builtin_amdgcn_mfma_f32_16x16x32_bf16(ah, bl, acc[c], 0, 0, 0);
        }
    }

    // C/D: row = (lane>>4)*4 + i, col = c*16 + (lane&15)
    const int rbase = row0 + ((lane >> 4) << 2);
    float d[4];
    #pragma unroll
    for (int i = 0; i < 4; ++i) d[i] = dis[rbase + i];
    #pragma unroll
    for (int c = 0; c < 8; ++c) {
        const int col = (c << 4) | lrow;
        #pragma unroll
        for (int i = 0; i < 4; ++i)
            hs[((long)(rbase + i) << 7) + col] = acc[c][i] * d[i];
    }
}

// ---------- gather-aggregate: one wave per node, 8-deep edge unroll ----------
// PROJ=false: write fp32 h. PROJ=true: write only pu/pv projections (h never materialized)
template<bool PROJ>
__global__ __launch_bounds__(256) void gather_agg_k(
    const int* __restrict__ rowptr, const int* __restrict__ csr,
    const float* __restrict__ hs, const float* __restrict__ dis,
    const float* __restrict__ b, float* __restrict__ o,
    const float* __restrict__ Wq, float* __restrict__ pu, float* __restrict__ pv, int N) {
    const int lane = threadIdx.x & 63;
    const int wid = (int)((blockIdx.x * (long)blockDim.x + threadIdx.x) >> 6);
    const int nw = (int)(((long)gridDim.x * blockDim.x) >> 6);
    const float2 bb = *reinterpret_cast<const float2*>(&b[lane * 2]);
    float2 wu = {0.f, 0.f}, wv = {0.f, 0.f};
    if constexpr (PROJ) {
        wu = *reinterpret_cast<const float2*>(&Wq[lane * 2]);
        wv = *reinterpret_cast<const float2*>(&Wq[HDIM + lane * 2]);
    }
    const int loff = lane * 2;
    for (int n = wid; n < N; n += nw) {
        const int r0 = rowptr[n], r1 = rowptr[n + 1];
        float2 acc = *reinterpret_cast<const float2*>(&hs[((long)n << 7) + loff]);
        float2 acc2 = {0.f, 0.f};
        int e = r0;
        for (; e + 8 <= r1; e += 8) {
            const int s0 = csr[e],     s1 = csr[e + 1], s2 = csr[e + 2], s3 = csr[e + 3];
            const int s4 = csr[e + 4], s5 = csr[e + 5], s6 = csr[e + 6], s7 = csr[e + 7];
            const float2 v0 = *reinterpret_cast<const float2*>(&hs[((long)s0 << 7) + loff]);
            const float2 v1 = *reinterpret_cast<const float2*>(&hs[((long)s1 << 7) + loff]);
            const float2 v2 = *reinterpret_cast<const float2*>(&hs[((long)s2 << 7) + loff]);
            const float2 v3 = *reinterpret_cast<const float2*>(&hs[((long)s3 << 7) + loff]);
            const float2 v4 = *reinterpret_cast<const float2*>(&hs[((long)s4 << 7) + loff]);
            const float2 v5 = *reinterpret_cast<const float2*>(&hs[((long)s5 << 7) + loff]);
            const float2 v6 = *reinterpret_cast<const float2*>(&hs[((long)s6 << 7) + loff]);
            const float2 v7 = *reinterpret_cast<const float2*>(&hs[((long)s7 << 7) + loff]);
            acc.x  += v0.x + v1.x;  acc.y  += v0.y + v1.y;
            acc2.x += v2.x + v3.x;  acc2.y += v2.y + v3.y;
            acc.x  += v4.x + v5.x;  acc.y  += v4.y + v5.y;
            acc2.x += v6.x + v7.x;  acc2.y += v6.y + v7.y;
        }
        for (; e + 2 <= r1; e += 2) {
            const int s0 = csr[e], s1 = csr[e + 1];
            const float2 v0 = *reinterpret_cast<const float2*>(&hs[((long)s0 << 7) + loff]);
            const float2 v1 = *reinterpret_cast<const float2*>(&hs[((long)s1 << 7) + loff]);
            acc.x += v0.x + v1.x;
            acc.y += v0.y + v1.y;
        }
        if (e < r1) {
            const int s0 = csr[e];
            const float2 v0 = *reinterpret_cast<const float2*>(&hs[((long)s0 << 7) + loff]);
            acc.x += v0.x;
            acc.y += v0.y;
        }
        acc.x += acc2.x;
        acc.y += acc2.y;
        const float dv = dis[n];
        const float o0 = fmaxf(fmaf(acc.x, dv, bb.x), 0.f);
        const float o1 = fmaxf(fmaf(acc.y, dv, bb.y), 0.f);
        if constexpr (!PROJ) {
            float2 ov = {o0, o1};
            *reinterpret_cast<float2*>(o + ((long)n << 7) + loff) = ov;
        } else {
            float su = o0 * wu.x + o1 * wu.y;
            float sv = o0 * wv.x + o1 * wv.y;
            #pragma unroll
            for (int off = 32; off > 0; off >>= 1) {
                su += __shfl_down(su, off, 64);
                sv += __shfl_down(sv, off, 64);
            }
            if (lane == 0) {
                pu[n] = su;
                pv[n] = sv;
            }
        }
    }
}

// ---------- Q head: out[a] = pu[va[a,0]] + pv[va[a,1]] + bq ----------
__global__ __launch_bounds__(256) void qhead_k(
    const float* __restrict__ pu, const float* __restrict__ pv,
    const int* __restrict__ va, const float* __restrict__ bq,
    float* __restrict__ out, int A) {
    const float bqv = bq[0];
    int i = blockIdx.x * blockDim.x + threadIdx.x;
    const int stride = gridDim.x * blockDim.x;
    for (; i < A; i += stride) {
        const int2 uv = reinterpret_cast<const int2*>(va)[i];
        out[i] = pu[uv.x] + pv[uv.y] + bqv;
    }
}

extern "C" void kernel_launch(void* const* d_in, const int* in_sizes, int n_in,
                              void* d_out, int out_size, void* d_ws, size_t ws_size,
                              hipStream_t stream) {
    const float* x   = (const float*)d_in[0];
    const int*   ei  = (const int*)d_in[1];     // [2][E] flat: src then dst
    const int*   va  = (const int*)d_in[2];     // [A][2]
    const float* W1  = (const float*)d_in[3];
    const float* b1  = (const float*)d_in[4];
    const float* W2  = (const float*)d_in[5];
    const float* b2  = (const float*)d_in[6];
    const float* Wq  = (const float*)d_in[7];
    const float* bq  = (const float*)d_in[8];
    float* out = (float*)d_out;

    const int N = in_sizes[0] / HDIM;       // 50000
    const int E = in_sizes[1] / 2;          // 600000
    const int A = in_sizes[2] / 2;          // 200000
    const int* esrc = ei;
    const int* edst = ei + E;

    const int Nal = (N + 63) & ~63;

    char* p = (char*)d_ws;
    auto alloc = [&](size_t bytes) { char* r = p; p += (bytes + 255) & ~(size_t)255; return r; };
    int* deg_i    = (int*)alloc((size_t)Nal * 4 * 2);  // deg | cursor adjacent -> one memset
    int* cursor   = deg_i + Nal;
    int* incl     = (int*)alloc((size_t)N * 4);
    int* rowptr   = (int*)alloc((size_t)(N + 1) * 4);
    int* blocksum = (int*)alloc(256 * 4);
    int* csr      = (int*)alloc((size_t)E * 4);
    float* dis    = (float*)alloc((size_t)N * 4);
    float* pu     = (float*)alloc((size_t)N * 4);
    float* pv     = (float*)alloc((size_t)N * 4);
    unsigned short* Wp1 = (unsigned short*)alloc(32768 * 2);
    unsigned short* Wp2 = (unsigned short*)alloc(32768 * 2);
    float* bufA   = (float*)alloc((size_t)N * HDIM * 4);   // hs (scaled GEMM out)
    float* bufB   = (float*)alloc((size_t)N * HDIM * 4);   // h1 fp32

    const int T = 256;
    const int NB = (N + 255) / 256;          // 196 (<= 256 required by merged scan)

    // --- CSR build + norms ---
    hipMemsetAsync(deg_i, 0, (size_t)Nal * 4 * 2, stream);   // deg + cursor in one shot
    deg_count_k<<<(E + T - 1) / T, T, 0, stream>>>(edst, deg_i, E);
    scan_part_k<<<NB, 256, 0, stream>>>(deg_i, incl, blocksum, N);
    scan_final_k<<<NB, 256, 0, stream>>>(deg_i, incl, blocksum, rowptr, dis, N, E, NB);
    fill_csr_k<<<(E + T - 1) / T, T, 0, stream>>>(esrc, edst, rowptr, cursor, csr, E);

    // --- weight pack (both layers, one kernel) ---
    pack_w2_k<<<128, 256, 0, stream>>>(W1, W2, Wp1, Wp2);

    // --- layer 1 ---
    mfma_gemm_k<<<(N + 127) / 128, 512, 0, stream>>>(x, Wp1, dis, bufA, N);
    gather_agg_k<false><<<2048, T, 0, stream>>>(rowptr, csr, bufA, dis, b1,
                                                bufB, nullptr, nullptr, nullptr, N);

    // --- layer 2 (gather fuses Q-projection epilogue; h2 never materialized) ---
    mfma_gemm_k<<<(N + 127) / 128, 512, 0, stream>>>(bufB, Wp2, dis, bufA, N);
    gather_agg_k<true><<<2048, T, 0, stream>>>(rowptr, csr, bufA, dis, b2,
                                               nullptr, Wq, pu, pv, N);

    // --- Q head ---
    qhead_k<<<512, T, 0, stream>>>(pu, pv, va, bq, out, A);
}